// Round 8
// baseline (70.793 us; speedup 1.0000x reference)
//
#include <hip/hip_runtime.h>
#include <stdint.h>

// maTransformerBlock fused kernel for MI355X (gfx950) — R7
//
// Shuffle algebra: with output batch b' = k*1024 + j (k in [0,32), j in [0,1024)):
//   source batch = 32 j + n', chunk = k.
// => block j handles source batches 32j..32j+31 and output batches {k*1024 + j}.
//
// R7 = R5 with the staging register round-trip replaced by global_load_lds DMA
// into double-buffered LDS (T3 minimal 2-phase). Per phase: 16 DMA issues (no
// dest VGPRs, no ds_writes) + ONE __syncthreads (its vmcnt(0) drain is the
// exact wait the dbuf needs). Prot phases run first (q result stays in regs),
// dna last; the attention d-plane overlays the stage buffers afterwards, so
// LDS = 33.8KB + 1KB -> 4 blocks/CU, grid 1024 = 4 x 256 CUs fully resident.
//
// DMA layout proof: per wave, dest = (s0+2k)*132 + (w&1)*64 + lane — wave-
// uniform base + lane*4, 256B contiguous inside the 132-float padded row
// (pad [104,132) absorbs clamped tail lanes pp in [103,128)). Conv reads
// (row stride 132 floats) stay bank-uniform as in R5.

constexpr int NB      = 32;
constexpr int THREADS = 256;
constexpr int NBLOCKS = 1024;

#define AS_GLB const __attribute__((address_space(1))) void
#define AS_LDS __attribute__((address_space(3))) void

__global__ __launch_bounds__(THREADS, 4)
void fused_matx(const float* __restrict__ dna,
                const float* __restrict__ prot,
                const float* __restrict__ wdna,
                const float* __restrict__ wprot,
                const float* __restrict__ wlin,
                const float* __restrict__ blin,
                float* __restrict__ out)
{
    // stage double-buffer (2 x 4224 floats = 33792B); after the last conv the
    // same memory is reused (barrier-separated) as the attention d-plane.
    __shared__ __align__(16) float s_mem[2 * 4224];
    __shared__ float2 s_red[128];                    // [wave][ob] partials, 1KB

    const int tid = threadIdx.x;
    const int j   = blockIdx.x;

    const int cs   = tid >> 3;        // conv row (source batch slot) 0..31
    const int xb   = tid & 7;         // conv x-block 0..7 (12 outputs)
    const int pp   = tid & 127;       // position within 2-row group
    const int s0   = tid >> 7;        // starting row (0/1), rows advance by 2/k
    const int half = (tid >> 6) & 1;  // which 64-float half of the row
    const int ppc  = (pp < 103) ? pp : 102;   // clamp: tail lanes re-load elt 102

    // per-lane global base for k=0; row k adds 2*rowlen
    const float* gd0 = dna  + (size_t)j * NB * 412  + s0 * 412  + ppc;
    const float* gp0 = prot + (size_t)j * NB * 2163 + s0 * 2163 + ppc;

    float* const l0a = &s_mem[       s0 * 132 + half * 64];   // buf0 wave dest
    float* const l0b = &s_mem[4224 + s0 * 132 + half * 64];   // buf1 wave dest
    const float* const bufA = &s_mem[0];
    const float* const bufB = &s_mem[4224];

    auto stage = [&](const float* g0, const int gstr, float* const l0) {
#pragma unroll
        for (int k = 0; k < 16; ++k)
            __builtin_amdgcn_global_load_lds((AS_GLB*)(g0 + (size_t)k * gstr),
                                             (AS_LDS*)(l0 + k * 264), 4, 0, 0);
    };
    auto conv8 = [&](const float* buf, const float* __restrict__ wsrc, int c,
                     float (&acc)[12]) {
        float w[8];
#pragma unroll
        for (int f = 0; f < 8; ++f) w[f] = wsrc[c * 8 + f];   // uniform -> SGPR
        float in[20];
        const float4* sp = reinterpret_cast<const float4*>(buf + cs * 132 + 12 * xb);
#pragma unroll
        for (int u = 0; u < 5; ++u) {                          // 5 aligned ds_read_b128
            float4 v = sp[u];
            in[4*u+0] = v.x; in[4*u+1] = v.y; in[4*u+2] = v.z; in[4*u+3] = v.w;
        }
#pragma unroll
        for (int f = 0; f < 8; ++f)
#pragma unroll
            for (int o = 0; o < 12; ++o)
                acc[o] = fmaf(in[o + f], w[f], acc[o]);
    };

    float dacc[12], pacc[12];
#pragma unroll
    for (int o = 0; o < 12; ++o) { dacc[o] = 0.f; pacc[o] = 0.f; }

    // ======== 25 DMA-pipelined phases: prot c0..c20, then dna c0..c3 ========
    stage(gp0, 4326, l0a);                        // t=0: prot c0 -> buf0
    __syncthreads();
    for (int c = 0; c < 20; c += 2) {
        stage(gp0 + (c + 1) * 103, 4326, l0b);    // t+1 -> buf1 (in flight)
        conv8(bufA, wprot, c, pacc);
        __syncthreads();                          // drains DMA + syncs
        stage(gp0 + (c + 2) * 103, 4326, l0a);    // t+2 -> buf0
        conv8(bufB, wprot, c + 1, pacc);
        __syncthreads();
    }
    stage(gd0, 824, l0b);                         // t=20: dna c0 -> buf1
    conv8(bufA, wprot, 20, pacc);
    __syncthreads();
    stage(gd0 + 103, 824, l0a);                   // t=21: dna c1 -> buf0
    conv8(bufB, wdna, 0, dacc);
    __syncthreads();
    stage(gd0 + 206, 824, l0b);                   // t=22: dna c2 -> buf1
    conv8(bufA, wdna, 1, dacc);
    __syncthreads();
    stage(gd0 + 309, 824, l0a);                   // t=23: dna c3 -> buf0
    conv8(bufB, wdna, 2, dacc);
    __syncthreads();
    conv8(bufA, wdna, 3, dacc);                   // t=24
    __syncthreads();                              // stage region free -> d4 overlay

    // ======== publish relu'd dna conv into the overlaid d-plane ========
    // layout [ob][slot = cs+xb], stride 40 float4 (20480B <= 33792B region)
    float4* const s_d4 = reinterpret_cast<float4*>(s_mem);
#pragma unroll
    for (int u = 0; u < 4; ++u) {
        float4 v;
        v.x = fmaxf(dacc[3*u+0], 0.f);
        v.y = fmaxf(dacc[3*u+1], 0.f);
        v.z = fmaxf(dacc[3*u+2], 0.f);
        v.w = 0.f;
        s_d4[(4 * xb + u) * 40 + cs + xb] = v;
    }
    __syncthreads();

    // ================= attention (32x32, d=3) + linear =================
    // thread (cs,xb): qr = cs (own pacc), ob = 4xb+it. d-reads: base + imm only.
    const float4* dp = s_d4 + 161 * xb;           // (4xb)*40 + xb
    float wl0[3], wl1[3];
#pragma unroll
    for (int t = 0; t < 3; ++t) {
        wl0[t] = wlin[3 * cs + t];
        wl1[t] = wlin[96 + 3 * cs + t];
    }
    const float escale = 0.5773502691896258f;     // 1/sqrt(3); logits bounded << 88

#pragma unroll
    for (int it = 0; it < 4; ++it) {
        const float q0 = fmaxf(pacc[3*it+0], 0.f);
        const float q1 = fmaxf(pacc[3*it+1], 0.f);
        const float q2 = fmaxf(pacc[3*it+2], 0.f);

        float sum = 0.f, v0 = 0.f, v1 = 0.f, v2 = 0.f;
#pragma unroll
        for (int r = 0; r < 32; ++r) {            // conflict-free broadcast b128
            float4 dv = dp[40 * it + r];          // = s_d4[ob*40 + (r+xb)] = row r
            float l = fmaf(q0, dv.x, fmaf(q1, dv.y, q2 * dv.z));
            float e = __expf(l * escale);
            sum += e;
            v0 = fmaf(e, dv.x, v0);
            v1 = fmaf(e, dv.y, v1);
            v2 = fmaf(e, dv.z, v2);
        }
        const float inv = 1.f / sum;
        float o0 = (wl0[0] * v0 + wl0[1] * v1 + wl0[2] * v2) * inv;
        float o1 = (wl1[0] * v0 + wl1[1] * v1 + wl1[2] * v2) * inv;
        // reduce over the 8 cs rows in this wave (lane bits 3..5)
        o0 += __shfl_xor(o0, 8);  o1 += __shfl_xor(o1, 8);
        o0 += __shfl_xor(o0, 16); o1 += __shfl_xor(o1, 16);
        o0 += __shfl_xor(o0, 32); o1 += __shfl_xor(o1, 32);
        if ((tid & 56) == 0)                      // one lane per (wave, xb)
            s_red[(tid >> 6) * 32 + 4 * xb + it] = make_float2(o0, o1);
    }
    __syncthreads();

    if (tid < 32) {                               // combine 4 wave-partials + bias
        float2 a = s_red[tid], b = s_red[32 + tid], c = s_red[64 + tid], d = s_red[96 + tid];
        float2 r;
        r.x = a.x + b.x + c.x + d.x + blin[0];
        r.y = a.y + b.y + c.y + d.y + blin[1];
        *reinterpret_cast<float2*>(&out[(size_t)((tid << 10) + j) * 2]) = r;
    }
}

extern "C" void kernel_launch(void* const* d_in, const int* in_sizes, int n_in,
                              void* d_out, int out_size, void* d_ws, size_t ws_size,
                              hipStream_t stream) {
    const float* dna   = (const float*)d_in[0];
    const float* prot  = (const float*)d_in[1];
    const float* wdna  = (const float*)d_in[2];
    const float* wprot = (const float*)d_in[3];
    const float* wlin  = (const float*)d_in[4];
    const float* blin  = (const float*)d_in[5];
    float* out = (float*)d_out;

    fused_matx<<<NBLOCKS, THREADS, 0, stream>>>(dna, prot, wdna, wprot, wlin, blin, out);
}

// Round 9
// 70.704 us; speedup vs baseline: 1.0013x; 1.0013x over previous
//
#include <hip/hip_runtime.h>
#include <stdint.h>

// maTransformerBlock fused kernel for MI355X (gfx950) — R7
//
// Shuffle algebra: with output batch b' = k*1024 + j (k in [0,32), j in [0,1024)):
//   source batch = 32 j + n', chunk = k.
// => block j handles source batches 32j..32j+31 and output batches {k*1024 + j}.
//
// R7 = R5 with the staging register round-trip replaced by global_load_lds DMA
// into double-buffered LDS (T3 minimal 2-phase). Per phase: 16 DMA issues (no
// dest VGPRs, no ds_writes) + ONE __syncthreads (its vmcnt(0) drain is the
// exact wait the dbuf needs). Prot phases run first (q result stays in regs),
// dna last; the attention d-plane overlays the stage buffers afterwards, so
// LDS = 33.8KB + 1KB -> 4 blocks/CU, grid 1024 = 4 x 256 CUs fully resident.
//
// DMA layout proof: per wave, dest = (s0+2k)*132 + (w&1)*64 + lane — wave-
// uniform base + lane*4, 256B contiguous inside the 132-float padded row
// (pad [104,132) absorbs clamped tail lanes pp in [103,128)). Conv reads
// (row stride 132 floats) stay bank-uniform as in R5.

constexpr int NB      = 32;
constexpr int THREADS = 256;
constexpr int NBLOCKS = 1024;

#define AS_GLB const __attribute__((address_space(1))) void
#define AS_LDS __attribute__((address_space(3))) void

__global__ __launch_bounds__(THREADS, 4)
void fused_matx(const float* __restrict__ dna,
                const float* __restrict__ prot,
                const float* __restrict__ wdna,
                const float* __restrict__ wprot,
                const float* __restrict__ wlin,
                const float* __restrict__ blin,
                float* __restrict__ out)
{
    // stage double-buffer (2 x 4224 floats = 33792B); after the last conv the
    // same memory is reused (barrier-separated) as the attention d-plane.
    __shared__ __align__(16) float s_mem[2 * 4224];
    __shared__ float2 s_red[128];                    // [wave][ob] partials, 1KB

    const int tid = threadIdx.x;
    const int j   = blockIdx.x;

    const int cs   = tid >> 3;        // conv row (source batch slot) 0..31
    const int xb   = tid & 7;         // conv x-block 0..7 (12 outputs)
    const int pp   = tid & 127;       // position within 2-row group
    const int s0   = tid >> 7;        // starting row (0/1), rows advance by 2/k
    const int half = (tid >> 6) & 1;  // which 64-float half of the row
    const int ppc  = (pp < 103) ? pp : 102;   // clamp: tail lanes re-load elt 102

    // per-lane global base for k=0; row k adds 2*rowlen
    const float* gd0 = dna  + (size_t)j * NB * 412  + s0 * 412  + ppc;
    const float* gp0 = prot + (size_t)j * NB * 2163 + s0 * 2163 + ppc;

    float* const l0a = &s_mem[       s0 * 132 + half * 64];   // buf0 wave dest
    float* const l0b = &s_mem[4224 + s0 * 132 + half * 64];   // buf1 wave dest
    const float* const bufA = &s_mem[0];
    const float* const bufB = &s_mem[4224];

    auto stage = [&](const float* g0, const int gstr, float* const l0) {
#pragma unroll
        for (int k = 0; k < 16; ++k)
            __builtin_amdgcn_global_load_lds((AS_GLB*)(g0 + (size_t)k * gstr),
                                             (AS_LDS*)(l0 + k * 264), 4, 0, 0);
    };
    auto conv8 = [&](const float* buf, const float* __restrict__ wsrc, int c,
                     float (&acc)[12]) {
        float w[8];
#pragma unroll
        for (int f = 0; f < 8; ++f) w[f] = wsrc[c * 8 + f];   // uniform -> SGPR
        float in[20];
        const float4* sp = reinterpret_cast<const float4*>(buf + cs * 132 + 12 * xb);
#pragma unroll
        for (int u = 0; u < 5; ++u) {                          // 5 aligned ds_read_b128
            float4 v = sp[u];
            in[4*u+0] = v.x; in[4*u+1] = v.y; in[4*u+2] = v.z; in[4*u+3] = v.w;
        }
#pragma unroll
        for (int f = 0; f < 8; ++f)
#pragma unroll
            for (int o = 0; o < 12; ++o)
                acc[o] = fmaf(in[o + f], w[f], acc[o]);
    };

    float dacc[12], pacc[12];
#pragma unroll
    for (int o = 0; o < 12; ++o) { dacc[o] = 0.f; pacc[o] = 0.f; }

    // ======== 25 DMA-pipelined phases: prot c0..c20, then dna c0..c3 ========
    stage(gp0, 4326, l0a);                        // t=0: prot c0 -> buf0
    __syncthreads();
    for (int c = 0; c < 20; c += 2) {
        stage(gp0 + (c + 1) * 103, 4326, l0b);    // t+1 -> buf1 (in flight)
        conv8(bufA, wprot, c, pacc);
        __syncthreads();                          // drains DMA + syncs
        stage(gp0 + (c + 2) * 103, 4326, l0a);    // t+2 -> buf0
        conv8(bufB, wprot, c + 1, pacc);
        __syncthreads();
    }
    stage(gd0, 824, l0b);                         // t=20: dna c0 -> buf1
    conv8(bufA, wprot, 20, pacc);
    __syncthreads();
    stage(gd0 + 103, 824, l0a);                   // t=21: dna c1 -> buf0
    conv8(bufB, wdna, 0, dacc);
    __syncthreads();
    stage(gd0 + 206, 824, l0b);                   // t=22: dna c2 -> buf1
    conv8(bufA, wdna, 1, dacc);
    __syncthreads();
    stage(gd0 + 309, 824, l0a);                   // t=23: dna c3 -> buf0
    conv8(bufB, wdna, 2, dacc);
    __syncthreads();
    conv8(bufA, wdna, 3, dacc);                   // t=24
    __syncthreads();                              // stage region free -> d4 overlay

    // ======== publish relu'd dna conv into the overlaid d-plane ========
    // layout [ob][slot = cs+xb], stride 40 float4 (20480B <= 33792B region)
    float4* const s_d4 = reinterpret_cast<float4*>(s_mem);
#pragma unroll
    for (int u = 0; u < 4; ++u) {
        float4 v;
        v.x = fmaxf(dacc[3*u+0], 0.f);
        v.y = fmaxf(dacc[3*u+1], 0.f);
        v.z = fmaxf(dacc[3*u+2], 0.f);
        v.w = 0.f;
        s_d4[(4 * xb + u) * 40 + cs + xb] = v;
    }
    __syncthreads();

    // ================= attention (32x32, d=3) + linear =================
    // thread (cs,xb): qr = cs (own pacc), ob = 4xb+it. d-reads: base + imm only.
    const float4* dp = s_d4 + 161 * xb;           // (4xb)*40 + xb
    float wl0[3], wl1[3];
#pragma unroll
    for (int t = 0; t < 3; ++t) {
        wl0[t] = wlin[3 * cs + t];
        wl1[t] = wlin[96 + 3 * cs + t];
    }
    const float escale = 0.5773502691896258f;     // 1/sqrt(3); logits bounded << 88

#pragma unroll
    for (int it = 0; it < 4; ++it) {
        const float q0 = fmaxf(pacc[3*it+0], 0.f);
        const float q1 = fmaxf(pacc[3*it+1], 0.f);
        const float q2 = fmaxf(pacc[3*it+2], 0.f);

        float sum = 0.f, v0 = 0.f, v1 = 0.f, v2 = 0.f;
#pragma unroll
        for (int r = 0; r < 32; ++r) {            // conflict-free broadcast b128
            float4 dv = dp[40 * it + r];          // = s_d4[ob*40 + (r+xb)] = row r
            float l = fmaf(q0, dv.x, fmaf(q1, dv.y, q2 * dv.z));
            float e = __expf(l * escale);
            sum += e;
            v0 = fmaf(e, dv.x, v0);
            v1 = fmaf(e, dv.y, v1);
            v2 = fmaf(e, dv.z, v2);
        }
        const float inv = 1.f / sum;
        float o0 = (wl0[0] * v0 + wl0[1] * v1 + wl0[2] * v2) * inv;
        float o1 = (wl1[0] * v0 + wl1[1] * v1 + wl1[2] * v2) * inv;
        // reduce over the 8 cs rows in this wave (lane bits 3..5)
        o0 += __shfl_xor(o0, 8);  o1 += __shfl_xor(o1, 8);
        o0 += __shfl_xor(o0, 16); o1 += __shfl_xor(o1, 16);
        o0 += __shfl_xor(o0, 32); o1 += __shfl_xor(o1, 32);
        if ((tid & 56) == 0)                      // one lane per (wave, xb)
            s_red[(tid >> 6) * 32 + 4 * xb + it] = make_float2(o0, o1);
    }
    __syncthreads();

    if (tid < 32) {                               // combine 4 wave-partials + bias
        float2 a = s_red[tid], b = s_red[32 + tid], c = s_red[64 + tid], d = s_red[96 + tid];
        float2 r;
        r.x = a.x + b.x + c.x + d.x + blin[0];
        r.y = a.y + b.y + c.y + d.y + blin[1];
        *reinterpret_cast<float2*>(&out[(size_t)((tid << 10) + j) * 2]) = r;
    }
}

extern "C" void kernel_launch(void* const* d_in, const int* in_sizes, int n_in,
                              void* d_out, int out_size, void* d_ws, size_t ws_size,
                              hipStream_t stream) {
    const float* dna   = (const float*)d_in[0];
    const float* prot  = (const float*)d_in[1];
    const float* wdna  = (const float*)d_in[2];
    const float* wprot = (const float*)d_in[3];
    const float* wlin  = (const float*)d_in[4];
    const float* blin  = (const float*)d_in[5];
    float* out = (float*)d_out;

    fused_matx<<<NBLOCKS, THREADS, 0, stream>>>(dna, prot, wdna, wprot, wlin, blin, out);
}

// Round 10
// 63.865 us; speedup vs baseline: 1.1085x; 1.1071x over previous
//
#include <hip/hip_runtime.h>

// maTransformerBlock fused kernel for MI355X (gfx950) — R9
//
// Shuffle algebra: with output batch b' = k*1024 + j (k in [0,32), j in [0,1024)):
//   source batch = 32 j + n', chunk = k.
// => block j handles source batches 32j..32j+31 and output batches {k*1024 + j}.
//
// R9: BARRIER-FREE conv. Wave w owns rows cs=8w..8w+7 (already true of the R5
// thread mapping), so each wave stages its own 8 rows of the current channel
// into a PRIVATE LDS region — no cross-wave dependency, no __syncthreads in
// the 25-phase conv loop (2 barriers total: d-plane publish, s_red). Waves
// free-run and desynchronize; HBM is fed continuously by 16 independent
// wave-streams/CU (~13 outstanding loads each) instead of barrier-edge bursts.
// Staging = register ping-pong: ld(p+1); st(p) [compiler emits counted
// vmcnt(13) -> next phase's loads stay in flight]; conv(p).
// Rows padded to 104 floats in LDS so conv ds_read_b128 stays 16B-aligned;
// per-lane (row,pos) split of the 824-float wave slab precomputed once.
// LDS 34.8 KB -> 4 blocks/CU; grid 1024 = 4 x 256 CUs fully resident.

constexpr int NB      = 32;
constexpr int THREADS = 256;
constexpr int NBLOCKS = 1024;

__global__ __launch_bounds__(THREADS, 4)
void fused_matx(const float* __restrict__ dna,
                const float* __restrict__ prot,
                const float* __restrict__ wdna,
                const float* __restrict__ wprot,
                const float* __restrict__ wlin,
                const float* __restrict__ blin,
                float* __restrict__ out)
{
    __shared__ __align__(16) float s_stage[4 * 832];   // 4 waves x 8 rows x 104f, 13312B
    __shared__ float4 s_d4[32 * 40];                   // [ob][slot=cs+xb], 20480B
    __shared__ float2 s_red[128];                      // [wave][ob] partials, 1024B

    const int tid  = threadIdx.x;
    const int j    = blockIdx.x;
    const int w    = tid >> 6;       // wave 0..3 (owns rows 8w..8w+7)
    const int lane = tid & 63;
    const int cs   = tid >> 3;       // conv row (source batch slot) 0..31
    const int xb   = tid & 7;        // conv x-block 0..7 (12 outputs)

    // ---- per-lane staging geometry (computed once) ----
    // wave slab per phase = 8 rows x 103 floats = 824; i = lane + 64k, k=0..12
    int gP[13], gD[13], lOf[13];
#pragma unroll
    for (int k = 0; k < 13; ++k) {
        int i = lane + 64 * k;
        if (i > 823) i = 823;            // tail lanes duplicate elt 823 (benign)
        int r = i / 103;                 // wave-local row 0..7 (magic-mul, once)
        int p = i - r * 103;
        gP[k]  = r * 2163 + p;           // prot global float offset (channel 0)
        gD[k]  = r * 412  + p;           // dna  global float offset (channel 0)
        lOf[k] = w * 832 + r * 104 + p;  // padded LDS slot
    }

    const float* dbase = dna  + (size_t)(j * NB + 8 * w) * 412;
    const float* pbase = prot + (size_t)(j * NB + 8 * w) * 2163;

    float pfA[13], pfB[13];

    auto ldP = [&](int c, float (&pf)[13]) {
        const float* b = pbase + c * 103;
#pragma unroll
        for (int k = 0; k < 13; ++k) pf[k] = b[gP[k]];
    };
    auto ldD = [&](int c, float (&pf)[13]) {
        const float* b = dbase + c * 103;
#pragma unroll
        for (int k = 0; k < 13; ++k) pf[k] = b[gD[k]];
    };
    auto st = [&](float (&pf)[13]) {
#pragma unroll
        for (int k = 0; k < 13; ++k) s_stage[lOf[k]] = pf[k];
    };
    auto conv8 = [&](const float* __restrict__ wsrc, int c, float (&acc)[12]) {
        float wv[8];
#pragma unroll
        for (int f = 0; f < 8; ++f) wv[f] = wsrc[c * 8 + f];   // uniform -> SGPR
        float in[20];
        const float4* sp = reinterpret_cast<const float4*>(
            &s_stage[w * 832 + (cs & 7) * 104 + 12 * xb]);     // 16B aligned
#pragma unroll
        for (int u = 0; u < 5; ++u) {                          // 5 ds_read_b128
            float4 v = sp[u];
            in[4*u+0] = v.x; in[4*u+1] = v.y; in[4*u+2] = v.z; in[4*u+3] = v.w;
        }
#pragma unroll
        for (int f = 0; f < 8; ++f)
#pragma unroll
            for (int o = 0; o < 12; ++o)
                acc[o] = fmaf(in[o + f], wv[f], acc[o]);
    };

    float dacc[12], pacc[12];
#pragma unroll
    for (int o = 0; o < 12; ++o) { dacc[o] = 0.f; pacc[o] = 0.f; }

    // ======== 25 barrier-free phases (prot 0..20, then dna 0..3) ========
    // pattern per phase t: ld(t+1) issue; st(t) [vmcnt(13): only t's loads
    // drained]; conv(t). Same-wave program order gives all needed hazards.
    ldP(0, pfA);
    ldP(1, pfB); st(pfA); conv8(wprot, 0, pacc);
    for (int c = 2; c < 20; c += 2) {
        ldP(c,     pfA); st(pfB); conv8(wprot, c - 1, pacc);
        ldP(c + 1, pfB); st(pfA); conv8(wprot, c,     pacc);
    }
    ldP(20, pfA); st(pfB); conv8(wprot, 19, pacc);
    ldD(0,  pfB); st(pfA); conv8(wprot, 20, pacc);
    ldD(1,  pfA); st(pfB); conv8(wdna, 0, dacc);
    ldD(2,  pfB); st(pfA); conv8(wdna, 1, dacc);
    ldD(3,  pfA); st(pfB); conv8(wdna, 2, dacc);
                  st(pfA); conv8(wdna, 3, dacc);

    // ======== publish relu'd dna conv to the d-plane ========
    // layout [ob][slot = cs+xb], stride 40 float4 (R5-verified, conflict-free)
#pragma unroll
    for (int u = 0; u < 4; ++u) {
        float4 v;
        v.x = fmaxf(dacc[3*u+0], 0.f);
        v.y = fmaxf(dacc[3*u+1], 0.f);
        v.z = fmaxf(dacc[3*u+2], 0.f);
        v.w = 0.f;
        s_d4[(4 * xb + u) * 40 + cs + xb] = v;
    }
    __syncthreads();                       // barrier #1 (of 2)

    // ================= attention (32x32, d=3) + linear =================
    // thread (cs,xb): qr = cs (own pacc), ob = 4xb+it. d-reads: base + imm only.
    const float4* dp = s_d4 + 161 * xb;    // (4xb)*40 + xb
    float wl0[3], wl1[3];
#pragma unroll
    for (int t = 0; t < 3; ++t) {
        wl0[t] = wlin[3 * cs + t];
        wl1[t] = wlin[96 + 3 * cs + t];
    }
    const float escale = 0.5773502691896258f;  // 1/sqrt(3); logits bounded << 88

#pragma unroll
    for (int it = 0; it < 4; ++it) {
        const float q0 = fmaxf(pacc[3*it+0], 0.f);
        const float q1 = fmaxf(pacc[3*it+1], 0.f);
        const float q2 = fmaxf(pacc[3*it+2], 0.f);

        float sum = 0.f, v0 = 0.f, v1 = 0.f, v2 = 0.f;
#pragma unroll
        for (int r = 0; r < 32; ++r) {     // conflict-free broadcast b128 reads
            float4 dv = dp[40 * it + r];   // = s_d4[ob*40 + (r+xb)] = row r of ob
            float l = fmaf(q0, dv.x, fmaf(q1, dv.y, q2 * dv.z));
            float e = __expf(l * escale);
            sum += e;
            v0 = fmaf(e, dv.x, v0);
            v1 = fmaf(e, dv.y, v1);
            v2 = fmaf(e, dv.z, v2);
        }
        const float inv = 1.f / sum;
        float o0 = (wl0[0] * v0 + wl0[1] * v1 + wl0[2] * v2) * inv;
        float o1 = (wl1[0] * v0 + wl1[1] * v1 + wl1[2] * v2) * inv;
        // reduce over the 8 cs rows in this wave (lane bits 3..5)
        o0 += __shfl_xor(o0, 8);  o1 += __shfl_xor(o1, 8);
        o0 += __shfl_xor(o0, 16); o1 += __shfl_xor(o1, 16);
        o0 += __shfl_xor(o0, 32); o1 += __shfl_xor(o1, 32);
        if ((tid & 56) == 0)               // one lane per (wave, xb)
            s_red[w * 32 + 4 * xb + it] = make_float2(o0, o1);
    }
    __syncthreads();                       // barrier #2 (of 2)

    if (tid < 32) {                        // combine 4 wave-partials + bias
        float2 a = s_red[tid], b = s_red[32 + tid], c = s_red[64 + tid], d = s_red[96 + tid];
        float2 r;
        r.x = a.x + b.x + c.x + d.x + blin[0];
        r.y = a.y + b.y + c.y + d.y + blin[1];
        *reinterpret_cast<float2*>(&out[(size_t)((tid << 10) + j) * 2]) = r;
    }
}

extern "C" void kernel_launch(void* const* d_in, const int* in_sizes, int n_in,
                              void* d_out, int out_size, void* d_ws, size_t ws_size,
                              hipStream_t stream) {
    const float* dna   = (const float*)d_in[0];
    const float* prot  = (const float*)d_in[1];
    const float* wdna  = (const float*)d_in[2];
    const float* wprot = (const float*)d_in[3];
    const float* wlin  = (const float*)d_in[4];
    const float* blin  = (const float*)d_in[5];
    float* out = (float*)d_out;

    fused_matx<<<NBLOCKS, THREADS, 0, stream>>>(dna, prot, wdna, wprot, wlin, blin, out);
}